// Round 1
// baseline (7232.185 us; speedup 1.0000x reference)
//
#include <hip/hip_runtime.h>
#include <math.h>

#define NNODES 50000
#define NEDGES 1600000
#define DIM    128
#define NHID   (NNODES * DIM)      // 6,400,000
#define TPB    256
#define NTILES ((NNODES + 63) / 64)   // 782, 64 rows per block-tile

// binned CSR
#define NBINS  196                 // ceil(50000/256)
#define BINSZ  256                 // nodes per bin (dst>>8)
#define EPT    16                  // edges per thread in binning passes
#define CHUNK  (TPB * EPT)         // 4096 edges per block
#define NCHUNKS ((NEDGES + CHUNK - 1) / CHUNK)   // 391

typedef unsigned short bf16_t;
typedef __attribute__((ext_vector_type(8))) short short8;   // 8 bf16, 4 VGPRs
typedef __attribute__((ext_vector_type(4))) float f32x4;    // MFMA acc

__device__ __forceinline__ float bf_lo(unsigned u) { return __uint_as_float(u << 16); }
__device__ __forceinline__ float bf_hi(unsigned u) { return __uint_as_float(u & 0xFFFF0000u); }
__device__ __forceinline__ bf16_t f2bf(float f) {   // RNE
    unsigned u = __float_as_uint(f);
    u += 0x7FFFu + ((u >> 16) & 1u);
    return (bf16_t)(u >> 16);
}
__device__ __forceinline__ unsigned pack2bf(float a, float b) {
    return (unsigned)f2bf(a) | ((unsigned)f2bf(b) << 16);
}

union S8U { short8 v; uint4 u4; unsigned us[4]; };

// ===========================================================================
// Binned CSR build: edges bucketed by bin = dst>>8 (256 nodes per bin).
// Packed entry u32 = (dst&255)<<16 | src  (both < 2^16).
//   bin_hist:    per-block LDS histogram -> 196 global counters
//   bin_scan:    one wave scans 196 counts -> start[197], cursor[196]
//   bin_scatter: per-block LDS-staged binning; each block reserves one
//                contiguous run per bin (1 global atomic) -> dense writes,
//                ~1.5x write amplification instead of 16x.
// ===========================================================================
__global__ __launch_bounds__(TPB) void bin_hist_kernel(
    const int* __restrict__ dst, int* __restrict__ gcnt)
{
    __shared__ int lcnt[NBINS];
    const int tid = threadIdx.x;
    for (int i = tid; i < NBINS; i += TPB) lcnt[i] = 0;
    __syncthreads();
    const int base = blockIdx.x * CHUNK;
    #pragma unroll
    for (int k = 0; k < EPT; ++k) {
        int e = base + k * TPB + tid;
        if (e < NEDGES) atomicAdd(&lcnt[dst[e] >> 8], 1);
    }
    __syncthreads();
    for (int i = tid; i < NBINS; i += TPB) {
        int c = lcnt[i];
        if (c) atomicAdd(&gcnt[i], c);
    }
}

__global__ __launch_bounds__(64) void bin_scan_kernel(
    const int* __restrict__ gcnt, int* __restrict__ start, int* __restrict__ bcur)
{
    const int lane = threadIdx.x;   // 64 lanes, each owns 4 bins
    int c[4];
    int s = 0;
    #pragma unroll
    for (int k = 0; k < 4; ++k) {
        int b = 4 * lane + k;
        c[k] = (b < NBINS) ? gcnt[b] : 0;
        s += c[k];
    }
    int incl = s;
    #pragma unroll
    for (int d = 1; d < 64; d <<= 1) {
        int t = __shfl_up(incl, d);
        if (lane >= d) incl += t;
    }
    int excl = incl - s;
    #pragma unroll
    for (int k = 0; k < 4; ++k) {
        int b = 4 * lane + k;
        if (b < NBINS) { start[b] = excl; bcur[b] = excl; }
        excl += c[k];
    }
    if (lane == 63) start[NBINS] = excl;   // == NEDGES
}

__global__ __launch_bounds__(TPB) void bin_scatter_kernel(
    const int* __restrict__ src, const int* __restrict__ dst,
    int* __restrict__ bcur, unsigned* __restrict__ bucket)
{
    __shared__ int lcnt[NBINS];    // phase A: counts
    __shared__ int lcur[NBINS];    // phase C: absolute cursors
    const int tid = threadIdx.x;
    for (int i = tid; i < NBINS; i += TPB) lcnt[i] = 0;
    __syncthreads();

    unsigned pk[EPT];
    int bn[EPT];
    const int base = blockIdx.x * CHUNK;
    #pragma unroll
    for (int k = 0; k < EPT; ++k) {
        int e = base + k * TPB + tid;
        int b = -1; unsigned p = 0;
        if (e < NEDGES) {
            int d = dst[e];
            int s = src[e];
            b = d >> 8;
            p = ((unsigned)(d & 255) << 16) | (unsigned)s;
            atomicAdd(&lcnt[b], 1);
        }
        pk[k] = p; bn[k] = b;
    }
    __syncthreads();
    for (int i = tid; i < NBINS; i += TPB) {
        int c = lcnt[i];
        lcur[i] = (c > 0) ? atomicAdd(&bcur[i], c) : 0;
    }
    __syncthreads();
    #pragma unroll
    for (int k = 0; k < EPT; ++k) {
        if (bn[k] >= 0) {
            int p = atomicAdd(&lcur[bn[k]], 1);
            bucket[p] = pk[k];
        }
    }
}

// ---------------------------------------------------------------------------
// Per-bin gather aggregation: one block per bin, 128 KB LDS f32 accumulator
// (256 rows x 128 cols). Per edge, one wave reads the 256B (bf16) / 512B
// (f32) source row and ds_add_f32's it into the dst row. Bank-swizzled
// layout (even cols at slots [0,64), odd at [64,128)) => every wave-wide
// LDS atomic is a free 2-way bank pattern.
// ---------------------------------------------------------------------------
__global__ __launch_bounds__(1024) void gather_bin_bf16_kernel(
    const bf16_t* __restrict__ hb, const int* __restrict__ start,
    const unsigned* __restrict__ bucket, float* __restrict__ agg)
{
    __shared__ float acc[BINSZ * DIM];   // 128 KB
    const int tid = threadIdx.x;
    const int b = blockIdx.x;
    for (int i = tid; i < BINSZ * DIM; i += 1024) acc[i] = 0.0f;
    __syncthreads();

    const int j0 = start[b], j1 = start[b + 1];
    const int lane = tid & 63, wv = tid >> 6;
    const unsigned* hrows = (const unsigned*)hb;   // 64 dwords per row

    for (int base = j0 + wv * 4; base < j1; base += 64) {
        const int eb = __builtin_amdgcn_readfirstlane(base);
        const int nk = min(4, j1 - eb);
        unsigned pk[4], uv[4];
        #pragma unroll
        for (int k = 0; k < 4; ++k)
            if (k < nk) pk[k] = bucket[eb + k];
        #pragma unroll
        for (int k = 0; k < 4; ++k)
            if (k < nk) uv[k] = hrows[(size_t)(pk[k] & 0xFFFFu) * 64 + lane];
        #pragma unroll
        for (int k = 0; k < 4; ++k) {
            if (k < nk) {
                int dl = (int)(pk[k] >> 16);
                atomicAdd(&acc[dl * 128 + lane],      bf_lo(uv[k]));   // col 2*lane
                atomicAdd(&acc[dl * 128 + 64 + lane], bf_hi(uv[k]));   // col 2*lane+1
            }
        }
    }
    __syncthreads();

    const int n0 = b * BINSZ;
    const int nn = min(BINSZ, NNODES - n0);
    for (int i = tid; i < nn * 64; i += 1024) {
        int row = i >> 6, s = i & 63;
        float2 w = make_float2(acc[row * 128 + s], acc[row * 128 + 64 + s]);
        *(float2*)(agg + (size_t)(n0 + row) * DIM + 2 * s) = w;
    }
}

__global__ __launch_bounds__(1024) void gather_bin_f32_kernel(
    const float* __restrict__ hx, const int* __restrict__ start,
    const unsigned* __restrict__ bucket, float* __restrict__ agg)
{
    __shared__ float acc[BINSZ * DIM];   // 128 KB
    const int tid = threadIdx.x;
    const int b = blockIdx.x;
    for (int i = tid; i < BINSZ * DIM; i += 1024) acc[i] = 0.0f;
    __syncthreads();

    const int j0 = start[b], j1 = start[b + 1];
    const int lane = tid & 63, wv = tid >> 6;
    const float2* hrows = (const float2*)hx;   // 64 float2 per row

    for (int base = j0 + wv * 4; base < j1; base += 64) {
        const int eb = __builtin_amdgcn_readfirstlane(base);
        const int nk = min(4, j1 - eb);
        unsigned pk[4];
        float2 uv[4];
        #pragma unroll
        for (int k = 0; k < 4; ++k)
            if (k < nk) pk[k] = bucket[eb + k];
        #pragma unroll
        for (int k = 0; k < 4; ++k)
            if (k < nk) uv[k] = hrows[(size_t)(pk[k] & 0xFFFFu) * 64 + lane];
        #pragma unroll
        for (int k = 0; k < 4; ++k) {
            if (k < nk) {
                int dl = (int)(pk[k] >> 16);
                atomicAdd(&acc[dl * 128 + lane],      uv[k].x);
                atomicAdd(&acc[dl * 128 + 64 + lane], uv[k].y);
            }
        }
    }
    __syncthreads();

    const int n0 = b * BINSZ;
    const int nn = min(BINSZ, NNODES - n0);
    for (int i = tid; i < nn * 64; i += 1024) {
        int row = i >> 6, s = i & 63;
        float2 w = make_float2(acc[row * 128 + s], acc[row * 128 + 64 + s]);
        *(float2*)(agg + (size_t)(n0 + row) * DIM + 2 * s) = w;
    }
}

// ---------------------------------------------------------------------------
// MFMA GEMM: out[50000x128] = f( z @ W + bias ), z = scale*hin + agg (opt).
//   mfma_f32_16x16x32_bf16. Block = 4 waves; wave owns 16 rows x 128 cols
//   (8 col-tiles). W^T staged bf16 in LDS [128][136] once/block; all 32
//   B-frags hoisted to VGPRs -> zero LDS traffic in the tile loop.
//   A-frags straight from global: A[m=lane&15][k=quad*8+j] = 16 B row chunk.
//   C/D: col=lane&15, row=quad*4+reg (HW-verified mapping).
//   SPLIT: z = z_hi + z_lo bf16 decomposition (fp32-accurate agg input).
//   MODE 0: y; 1: sigmoid(y); 2: layernorm(y)*gamma+beta (fp32 out).
// In-place safe: block reads only rows it owns, stores after its loads.
// ---------------------------------------------------------------------------
template <class HinT, class HoutT, int MODE, bool HAS_AGG, bool SPLIT>
__global__ __launch_bounds__(TPB) void mfma_gemm_kernel(
    const HinT* __restrict__ hin, const float* __restrict__ agg,
    const float* __restrict__ eps_ptr, int eps_idx,
    const float* __restrict__ W, const float* __restrict__ bias,
    const float* __restrict__ gamma, const float* __restrict__ beta,
    HoutT* __restrict__ out)
{
    __shared__ short sWt[128 * 136];   // bf16 W^T, padded row: 34.8 KB

    const int tid = threadIdx.x;
    // ---- stage W^T (fp32 -> bf16, transpose) ----
    #pragma unroll
    for (int it = 0; it < 8; ++it) {
        int idx = it * 256 + tid;
        int n = idx & 127, koct = idx >> 7;   // k octet
        float f[8];
        #pragma unroll
        for (int j = 0; j < 8; ++j) f[j] = W[(8 * koct + j) * 128 + n];
        uint4 u;
        u.x = pack2bf(f[0], f[1]); u.y = pack2bf(f[2], f[3]);
        u.z = pack2bf(f[4], f[5]); u.w = pack2bf(f[6], f[7]);
        *(uint4*)&sWt[n * 136 + 8 * koct] = u;
    }
    __syncthreads();

    const int lane = tid & 63, w = tid >> 6;
    const int m = lane & 15, quad = lane >> 4;

    // ---- hoist all B-fragments: bf[c*4+k0] = W^T[16c+m][32k0+8quad ..+7] ----
    short8 bf[32];
    #pragma unroll
    for (int c = 0; c < 8; ++c)
        #pragma unroll
        for (int k0 = 0; k0 < 4; ++k0)
            bf[c * 4 + k0] = *(const short8*)&sWt[(16 * c + m) * 136 + 32 * k0 + 8 * quad];

    const float scale = HAS_AGG ? (1.0f + eps_ptr[eps_idx]) : 1.0f;

    float bias_v[8];
    #pragma unroll
    for (int c = 0; c < 8; ++c) bias_v[c] = bias[16 * c + m];
    float g_v[8], bt_v[8];
    if (MODE == 2) {
        #pragma unroll
        for (int c = 0; c < 8; ++c) { g_v[c] = gamma[16 * c + m]; bt_v[c] = beta[16 * c + m]; }
    }

    for (int t = blockIdx.x; t < NTILES; t += gridDim.x) {
        const int arow = min(t * 64 + 16 * w + m, NNODES - 1);
        const size_t rbase = (size_t)arow * DIM;

        // ---- A-fragments (global), optional agg combine + hi/lo split ----
        short8 afh[4], afl[4];
        #pragma unroll
        for (int k0 = 0; k0 < 4; ++k0) {
            const int kb = 32 * k0 + 8 * quad;
            if (!HAS_AGG && sizeof(HinT) == 2) {
                afh[k0] = *(const short8*)((const bf16_t*)hin + rbase + kb);
            } else {
                float zf[8];
                if constexpr (sizeof(HinT) == 4) {
                    float4 h0 = *(const float4*)((const float*)hin + rbase + kb);
                    float4 h1 = *(const float4*)((const float*)hin + rbase + kb + 4);
                    zf[0] = h0.x; zf[1] = h0.y; zf[2] = h0.z; zf[3] = h0.w;
                    zf[4] = h1.x; zf[5] = h1.y; zf[6] = h1.z; zf[7] = h1.w;
                } else {
                    uint4 hu = *(const uint4*)((const bf16_t*)hin + rbase + kb);
                    zf[0] = bf_lo(hu.x); zf[1] = bf_hi(hu.x);
                    zf[2] = bf_lo(hu.y); zf[3] = bf_hi(hu.y);
                    zf[4] = bf_lo(hu.z); zf[5] = bf_hi(hu.z);
                    zf[6] = bf_lo(hu.w); zf[7] = bf_hi(hu.w);
                }
                if (HAS_AGG) {
                    float4 a0 = *(const float4*)(agg + rbase + kb);
                    float4 a1 = *(const float4*)(agg + rbase + kb + 4);
                    zf[0] = fmaf(scale, zf[0], a0.x); zf[1] = fmaf(scale, zf[1], a0.y);
                    zf[2] = fmaf(scale, zf[2], a0.z); zf[3] = fmaf(scale, zf[3], a0.w);
                    zf[4] = fmaf(scale, zf[4], a1.x); zf[5] = fmaf(scale, zf[5], a1.y);
                    zf[6] = fmaf(scale, zf[6], a1.z); zf[7] = fmaf(scale, zf[7], a1.w);
                }
                S8U hi;
                hi.us[0] = pack2bf(zf[0], zf[1]); hi.us[1] = pack2bf(zf[2], zf[3]);
                hi.us[2] = pack2bf(zf[4], zf[5]); hi.us[3] = pack2bf(zf[6], zf[7]);
                afh[k0] = hi.v;
                if (SPLIT) {
                    S8U lo;
                    float lw[8];
                    lw[0] = zf[0] - bf_lo(hi.us[0]); lw[1] = zf[1] - bf_hi(hi.us[0]);
                    lw[2] = zf[2] - bf_lo(hi.us[1]); lw[3] = zf[3] - bf_hi(hi.us[1]);
                    lw[4] = zf[4] - bf_lo(hi.us[2]); lw[5] = zf[5] - bf_hi(hi.us[2]);
                    lw[6] = zf[6] - bf_lo(hi.us[3]); lw[7] = zf[7] - bf_hi(hi.us[3]);
                    lo.us[0] = pack2bf(lw[0], lw[1]); lo.us[1] = pack2bf(lw[2], lw[3]);
                    lo.us[2] = pack2bf(lw[4], lw[5]); lo.us[3] = pack2bf(lw[6], lw[7]);
                    afl[k0] = lo.v;
                }
            }
        }

        // ---- MFMA ----
        f32x4 acc[8];
        #pragma unroll
        for (int c = 0; c < 8; ++c) acc[c] = (f32x4){0.f, 0.f, 0.f, 0.f};
        #pragma unroll
        for (int k0 = 0; k0 < 4; ++k0) {
            if (SPLIT) {
                #pragma unroll
                for (int c = 0; c < 8; ++c)
                    acc[c] = __builtin_amdgcn_mfma_f32_16x16x32_bf16(
                        afl[k0], bf[c * 4 + k0], acc[c], 0, 0, 0);
            }
            #pragma unroll
            for (int c = 0; c < 8; ++c)
                acc[c] = __builtin_amdgcn_mfma_f32_16x16x32_bf16(
                    afh[k0], bf[c * 4 + k0], acc[c], 0, 0, 0);
        }

        // ---- epilogue: row = t*64 + 16w + 4*quad + r, col = 16c + m ----
        const int row0 = t * 64 + 16 * w + 4 * quad;
        #pragma unroll
        for (int r = 0; r < 4; ++r) {
            const int grow = row0 + r;
            const bool ok = grow < NNODES;
            float y[8];
            #pragma unroll
            for (int c = 0; c < 8; ++c) y[c] = acc[c][r] + bias_v[c];
            if (MODE == 1) {
                #pragma unroll
                for (int c = 0; c < 8; ++c) y[c] = 1.0f / (1.0f + expf(-y[c]));
            } else if (MODE == 2) {
                float s1 = 0.f, s2 = 0.f;
                #pragma unroll
                for (int c = 0; c < 8; ++c) { s1 += y[c]; s2 = fmaf(y[c], y[c], s2); }
                #pragma unroll
                for (int d = 1; d < 16; d <<= 1) {   // reduce across 16-lane col group
                    s1 += __shfl_xor(s1, d);
                    s2 += __shfl_xor(s2, d);
                }
                float mean = s1 * (1.0f / DIM);
                float var  = s2 * (1.0f / DIM) - mean * mean;
                float rstd = rsqrtf(var + 1e-5f);
                #pragma unroll
                for (int c = 0; c < 8; ++c)
                    y[c] = fmaf((y[c] - mean) * rstd, g_v[c], bt_v[c]);
            }
            if (ok) {
                if constexpr (sizeof(HoutT) == 4) {
                    float* op = (float*)out + (size_t)grow * DIM + m;
                    #pragma unroll
                    for (int c = 0; c < 8; ++c) op[16 * c] = y[c];
                } else {
                    bf16_t* op = (bf16_t*)out + (size_t)grow * DIM + m;
                    #pragma unroll
                    for (int c = 0; c < 8; ++c) op[16 * c] = f2bf(y[c]);
                }
            }
        }
    }
}

// ---------------------------------------------------------------------------
// samples = mean + eps*std; eps = jax.random.normal(key(42)), partitionable
// threefry: block inputs (0, i), bits = out0 ^ out1, key (0,42).
// ---------------------------------------------------------------------------
__device__ __forceinline__ unsigned rotl32(unsigned x, int r) {
    return (x << r) | (x >> (32 - r));
}

__device__ __forceinline__ unsigned threefry_xor(unsigned c0, unsigned c1) {
    const unsigned k0 = 0u, k1 = 42u;
    const unsigned k2 = k0 ^ k1 ^ 0x1BD11BDAu;
    unsigned x0 = c0 + k0;
    unsigned x1 = c1 + k1;
#define TF_ROUND(R) { x0 += x1; x1 = rotl32(x1, R); x1 ^= x0; }
    TF_ROUND(13) TF_ROUND(15) TF_ROUND(26) TF_ROUND(6)
    x0 += k1; x1 += k2 + 1u;
    TF_ROUND(17) TF_ROUND(29) TF_ROUND(16) TF_ROUND(24)
    x0 += k2; x1 += k0 + 2u;
    TF_ROUND(13) TF_ROUND(15) TF_ROUND(26) TF_ROUND(6)
    x0 += k0; x1 += k1 + 3u;
    TF_ROUND(17) TF_ROUND(29) TF_ROUND(16) TF_ROUND(24)
    x0 += k1; x1 += k2 + 4u;
    TF_ROUND(13) TF_ROUND(15) TF_ROUND(26) TF_ROUND(6)
    x0 += k2; x1 += k0 + 5u;
#undef TF_ROUND
    return x0 ^ x1;
}

__device__ __forceinline__ float bits_to_normal(unsigned bits) {
    float f = __uint_as_float((bits >> 9) | 0x3F800000u) - 1.0f;
    const float lo = -0.99999994f;
    float u = __fadd_rn(__fmul_rn(f, 2.0f), lo);
    u = fmaxf(lo, u);
    float w = -log1pf(-(u * u));
    float p;
    if (w < 5.0f) {
        w -= 2.5f;
        p = 2.81022636e-08f;
        p = fmaf(p, w, 3.43273939e-07f);
        p = fmaf(p, w, -3.5233877e-06f);
        p = fmaf(p, w, -4.39150654e-06f);
        p = fmaf(p, w, 0.00021858087f);
        p = fmaf(p, w, -0.00125372503f);
        p = fmaf(p, w, -0.00417768164f);
        p = fmaf(p, w, 0.246640727f);
        p = fmaf(p, w, 1.50140941f);
    } else {
        w = sqrtf(w) - 3.0f;
        p = -0.000200214257f;
        p = fmaf(p, w, 0.000100950558f);
        p = fmaf(p, w, 0.00134934322f);
        p = fmaf(p, w, -0.00367342844f);
        p = fmaf(p, w, 0.00573950773f);
        p = fmaf(p, w, -0.0076224613f);
        p = fmaf(p, w, 0.00943887047f);
        p = fmaf(p, w, 1.00167406f);
        p = fmaf(p, w, 2.83297682f);
    }
    return 1.41421356f * (p * u);
}

__global__ __launch_bounds__(TPB) void samples_kernel(
    const float* __restrict__ mean_v, const float* __restrict__ std_v,
    float* __restrict__ samples)
{
    int t = blockIdx.x * TPB + threadIdx.x;
    if (t >= NHID / 4) return;
    float4 m = ((const float4*)mean_v)[t];
    float4 s = ((const float4*)std_v)[t];
    float e[4];
    #pragma unroll
    for (int q = 0; q < 4; q++) {
        unsigned i = 4u * (unsigned)t + (unsigned)q;
        e[q] = bits_to_normal(threefry_xor(0u, i));
    }
    float4 r;
    r.x = fmaf(e[0], s.x, m.x);
    r.y = fmaf(e[1], s.y, m.y);
    r.z = fmaf(e[2], s.z, m.z);
    r.w = fmaf(e[3], s.w, m.w);
    ((float4*)samples)[t] = r;
}

// ---------------------------------------------------------------------------
// Orchestration:
//   Binned CSR (hist196 -> scan196 -> scatter) replaces per-node CSR;
//   gathers accumulate per-bin in 128 KB LDS (ds_add_f32).
//   S region: bf16 h during GIN, fp32 samples at the end.
//   M: p0 aggs then mean_v.  V: shared l0 agg, p1 aggs, then std_v.
//   d_ws: gcnt[196] | start[197] | bcur[196] | bucket[NEDGES] (~6.4 MB).
// ---------------------------------------------------------------------------
extern "C" void kernel_launch(void* const* d_in, const int* in_sizes, int n_in,
                              void* d_out, int out_size, void* d_ws, size_t ws_size,
                              hipStream_t stream)
{
    const float* x     = (const float*)d_in[0];
    const int*   esrc  = (const int*)d_in[1];
    const int*   edst  = (const int*)d_in[2];
    const float* prm[2][7];
    for (int p = 0; p < 2; p++)
        for (int i = 0; i < 7; i++)
            prm[p][i] = (const float*)d_in[3 + p * 7 + i];
    const float* gamma = (const float*)d_in[17];
    const float* beta  = (const float*)d_in[18];

    float*  S  = (float*)d_out;
    bf16_t* Sb = (bf16_t*)d_out;
    float*  M  = S + NHID;
    float*  V  = M + NHID;

    int* gcnt  = (int*)d_ws;                       // NBINS
    int* start = gcnt + NBINS;                     // NBINS + 1
    int* bcur  = start + NBINS + 1;                // NBINS
    unsigned* bucket = (unsigned*)(bcur + NBINS);  // NEDGES packed entries

    const dim3 gChunk(NCHUNKS);
    const dim3 gBin(NBINS);
    const dim3 gGemm(512);
    const dim3 gSamp((NHID / 4 + TPB - 1) / TPB);

    hipMemsetAsync(gcnt, 0, NBINS * sizeof(int), stream);
    bin_hist_kernel<<<gChunk, TPB, 0, stream>>>(edst, gcnt);
    bin_scan_kernel<<<1, 64, 0, stream>>>(gcnt, start, bcur);
    bin_scatter_kernel<<<gChunk, TPB, 0, stream>>>(esrc, edst, bcur, bucket);

    // shared layer-0 aggregation (fp32 x)
    gather_bin_f32_kernel<<<gBin, 1024, 0, stream>>>(x, start, bucket, V);

    for (int p = 0; p < 2; p++) {
        const float* W1  = prm[p][0];
        const float* b1  = prm[p][1];
        const float* W2  = prm[p][2];
        const float* b2  = prm[p][3];
        const float* eps = prm[p][4];
        const float* Wo  = prm[p][5];
        const float* bo  = prm[p][6];
        float* AGG = (p == 0) ? M : V;
        float* OUT = (p == 0) ? M : V;

        // layer 0: fp32 x + shared agg (V), sigmoid, -> bf16 h
        mfma_gemm_kernel<float, bf16_t, 1, true, true><<<gGemm, TPB, 0, stream>>>(
            x, V, eps, 0, W1, b1, nullptr, nullptr, Sb);
        mfma_gemm_kernel<bf16_t, bf16_t, 0, false, false><<<gGemm, TPB, 0, stream>>>(
            Sb, nullptr, nullptr, 0, W2, b2, nullptr, nullptr, Sb);

        for (int l = 1; l < 3; l++) {
            gather_bin_bf16_kernel<<<gBin, 1024, 0, stream>>>(Sb, start, bucket, AGG);
            mfma_gemm_kernel<bf16_t, bf16_t, 1, true, true><<<gGemm, TPB, 0, stream>>>(
                Sb, AGG, eps, l, W1 + (size_t)l * DIM * DIM, b1 + l * DIM,
                nullptr, nullptr, Sb);
            mfma_gemm_kernel<bf16_t, bf16_t, 0, false, false><<<gGemm, TPB, 0, stream>>>(
                Sb, nullptr, nullptr, 0, W2 + (size_t)l * DIM * DIM, b2 + l * DIM,
                nullptr, nullptr, Sb);
        }

        mfma_gemm_kernel<bf16_t, float, 2, false, false><<<gGemm, TPB, 0, stream>>>(
            Sb, nullptr, nullptr, 0, Wo, bo, gamma, beta, OUT);
    }

    samples_kernel<<<gSamp, TPB, 0, stream>>>(M, V, S);
}

// Round 2
// 849.429 us; speedup vs baseline: 8.5142x; 8.5142x over previous
//
#include <hip/hip_runtime.h>
#include <math.h>

#define NNODES 50000
#define NEDGES 1600000
#define DIM    128
#define NHID   (NNODES * DIM)      // 6,400,000
#define TPB    256
#define NTILES ((NNODES + 63) / 64)   // 782, 64 rows per block-tile

// binned CSR build
#define NBINS  196                 // ceil(50000/256)
#define BINSZ  256                 // nodes per bin (dst>>8)
#define EPT    16                  // edges per thread in binning passes
#define CHUNK  (TPB * EPT)         // 4096 edges per block
#define NCHUNKS ((NEDGES + CHUNK - 1) / CHUNK)   // 391
#define BINCAP 10240               // staged edges per bin (mean 8192, sigma 90)

typedef unsigned short bf16_t;
typedef __attribute__((ext_vector_type(8))) short short8;   // 8 bf16, 4 VGPRs
typedef __attribute__((ext_vector_type(4))) float f32x4;    // MFMA acc

__device__ __forceinline__ float bf_lo(unsigned u) { return __uint_as_float(u << 16); }
__device__ __forceinline__ float bf_hi(unsigned u) { return __uint_as_float(u & 0xFFFF0000u); }
__device__ __forceinline__ bf16_t f2bf(float f) {   // RNE
    unsigned u = __float_as_uint(f);
    u += 0x7FFFu + ((u >> 16) & 1u);
    return (bf16_t)(u >> 16);
}
__device__ __forceinline__ unsigned pack2bf(float a, float b) {
    return (unsigned)f2bf(a) | ((unsigned)f2bf(b) << 16);
}

union S8U { short8 v; uint4 u4; unsigned us[4]; };

// ===========================================================================
// CSR build, dense-write pipeline:
//   bin_hist:    per-block LDS histogram of bin = dst>>8 -> 196 counters
//   bin_scan:    one wave scans 196 counts -> start[197], bcur; off[N]=NE
//   bin_scatter: per-block LDS-staged binning, one contiguous reservation
//                per bin per block -> dense packed writes (dl<<16 | src)
//   build_csr:   block per bin: stage edges in LDS, counting-sort by local
//                dst, emit per-node off[] and in-place sorted src bucket.
// All scattered 4B writes land in an L2-resident 32-40KB window => ~1x
// write amplification (vs 16x for the old per-node bucket_kernel).
// ===========================================================================
__global__ __launch_bounds__(TPB) void bin_hist_kernel(
    const int* __restrict__ dst, int* __restrict__ gcnt)
{
    __shared__ int lcnt[NBINS];
    const int tid = threadIdx.x;
    for (int i = tid; i < NBINS; i += TPB) lcnt[i] = 0;
    __syncthreads();
    const int base = blockIdx.x * CHUNK;
    #pragma unroll
    for (int k = 0; k < EPT; ++k) {
        int e = base + k * TPB + tid;
        if (e < NEDGES) atomicAdd(&lcnt[dst[e] >> 8], 1);
    }
    __syncthreads();
    for (int i = tid; i < NBINS; i += TPB) {
        int c = lcnt[i];
        if (c) atomicAdd(&gcnt[i], c);
    }
}

__global__ __launch_bounds__(64) void bin_scan_kernel(
    const int* __restrict__ gcnt, int* __restrict__ start, int* __restrict__ bcur,
    int* __restrict__ off)
{
    const int lane = threadIdx.x;   // 64 lanes, each owns 4 bins
    int c[4];
    int s = 0;
    #pragma unroll
    for (int k = 0; k < 4; ++k) {
        int b = 4 * lane + k;
        c[k] = (b < NBINS) ? gcnt[b] : 0;
        s += c[k];
    }
    int incl = s;
    #pragma unroll
    for (int d = 1; d < 64; d <<= 1) {
        int t = __shfl_up(incl, d);
        if (lane >= d) incl += t;
    }
    int excl = incl - s;
    #pragma unroll
    for (int k = 0; k < 4; ++k) {
        int b = 4 * lane + k;
        if (b < NBINS) { start[b] = excl; bcur[b] = excl; }
        excl += c[k];
    }
    if (lane == 63) { start[NBINS] = excl; off[NNODES] = excl; }   // == NEDGES
}

__global__ __launch_bounds__(TPB) void bin_scatter_kernel(
    const int* __restrict__ src, const int* __restrict__ dst,
    int* __restrict__ bcur, unsigned* __restrict__ bucket)
{
    __shared__ int lcnt[NBINS];    // phase A: counts
    __shared__ int lcur[NBINS];    // phase C: absolute cursors
    const int tid = threadIdx.x;
    for (int i = tid; i < NBINS; i += TPB) lcnt[i] = 0;
    __syncthreads();

    unsigned pk[EPT];
    int bn[EPT];
    const int base = blockIdx.x * CHUNK;
    #pragma unroll
    for (int k = 0; k < EPT; ++k) {
        int e = base + k * TPB + tid;
        int b = -1; unsigned p = 0;
        if (e < NEDGES) {
            int d = dst[e];
            int s = src[e];
            b = d >> 8;
            p = ((unsigned)(d & 255) << 16) | (unsigned)s;
            atomicAdd(&lcnt[b], 1);
        }
        pk[k] = p; bn[k] = b;
    }
    __syncthreads();
    for (int i = tid; i < NBINS; i += TPB) {
        int c = lcnt[i];
        lcur[i] = (c > 0) ? atomicAdd(&bcur[i], c) : 0;
    }
    __syncthreads();
    #pragma unroll
    for (int k = 0; k < EPT; ++k) {
        if (bn[k] >= 0) {
            int p = atomicAdd(&lcur[bn[k]], 1);
            bucket[p] = pk[k];
        }
    }
}

__global__ __launch_bounds__(TPB) void build_csr_kernel(
    const int* __restrict__ start, unsigned* __restrict__ bucket,
    int* __restrict__ off)
{
    __shared__ unsigned se[BINCAP];   // staged bin edges, 40 KB
    __shared__ int lcnt[BINSZ];
    __shared__ int lofs[BINSZ];
    __shared__ int wsum[4];
    const int tid = threadIdx.x;
    const int b = blockIdx.x;
    const int j0 = start[b], j1 = start[b + 1];
    const int n = j1 - j0;            // <= BINCAP by construction

    lcnt[tid] = 0;
    for (int i = tid; i < n; i += TPB) se[i] = bucket[j0 + i];
    __syncthreads();
    for (int i = tid; i < n; i += TPB) atomicAdd(&lcnt[se[i] >> 16], 1);
    __syncthreads();

    // exclusive scan of lcnt[256] across 4 waves
    const int lane = tid & 63, wid = tid >> 6;
    int v = lcnt[tid];
    int s = v;
    #pragma unroll
    for (int d = 1; d < 64; d <<= 1) {
        int t = __shfl_up(s, d);
        if (lane >= d) s += t;
    }
    if (lane == 63) wsum[wid] = s;
    __syncthreads();
    if (tid == 0) {
        int a = 0;
        #pragma unroll
        for (int k = 0; k < 4; ++k) { int t = wsum[k]; wsum[k] = a; a += t; }
    }
    __syncthreads();
    int excl = wsum[wid] + s - v;
    lofs[tid] = excl;
    int node = b * BINSZ + tid;
    if (node < NNODES) off[node] = j0 + excl;
    __syncthreads();

    // in-place counting-sort scatter (safe: all edges staged in LDS)
    for (int i = tid; i < n; i += TPB) {
        unsigned e = se[i];
        int pos = atomicAdd(&lofs[e >> 16], 1);
        bucket[j0 + pos] = e & 0xFFFFu;   // src node id
    }
}

// ---------------------------------------------------------------------------
// Gather aggregation, wave per node (round-0 proven structure).
// ---------------------------------------------------------------------------
__global__ __launch_bounds__(TPB) void gather_agg_f32_kernel(
    const float* __restrict__ h, const int* __restrict__ off,
    const unsigned* __restrict__ bucket, float* __restrict__ agg)
{
    int node = blockIdx.x * (TPB / 64) + (threadIdx.x >> 6);
    int lane = threadIdx.x & 63;
    if (node >= NNODES) return;
    int j0 = off[node], j1 = off[node + 1];
    const float* base = h + 2 * lane;
    float ax = 0.0f, ay = 0.0f;
    int j = j0;
    for (; j + 1 < j1; j += 2) {
        unsigned s0 = bucket[j], s1 = bucket[j + 1];
        float2 v0 = *(const float2*)(base + (size_t)s0 * DIM);
        float2 v1 = *(const float2*)(base + (size_t)s1 * DIM);
        ax += v0.x; ay += v0.y;
        ax += v1.x; ay += v1.y;
    }
    if (j < j1) {
        float2 v0 = *(const float2*)(base + (size_t)bucket[j] * DIM);
        ax += v0.x; ay += v0.y;
    }
    *(float2*)(agg + (size_t)node * DIM + 2 * lane) = make_float2(ax, ay);
}

__global__ __launch_bounds__(TPB) void gather_agg_bf16_kernel(
    const bf16_t* __restrict__ hb, const int* __restrict__ off,
    const unsigned* __restrict__ bucket, float* __restrict__ agg)
{
    int node = blockIdx.x * (TPB / 64) + (threadIdx.x >> 6);
    int lane = threadIdx.x & 63;
    if (node >= NNODES) return;
    int j0 = off[node], j1 = off[node + 1];
    const unsigned* base = (const unsigned*)hb + lane;
    float ax = 0.0f, ay = 0.0f;
    int j = j0;
    for (; j + 1 < j1; j += 2) {
        unsigned s0 = bucket[j], s1 = bucket[j + 1];
        unsigned u0 = base[(size_t)s0 * (DIM / 2)];
        unsigned u1 = base[(size_t)s1 * (DIM / 2)];
        ax += bf_lo(u0); ay += bf_hi(u0);
        ax += bf_lo(u1); ay += bf_hi(u1);
    }
    if (j < j1) {
        unsigned u0 = base[(size_t)bucket[j] * (DIM / 2)];
        ax += bf_lo(u0); ay += bf_hi(u0);
    }
    *(float2*)(agg + (size_t)node * DIM + 2 * lane) = make_float2(ax, ay);
}

// ---------------------------------------------------------------------------
// MFMA GEMM: out[50000x128] = f( z @ W + bias ), z = scale*hin + agg (opt).
//   mfma_f32_16x16x32_bf16. Block = 4 waves; wave owns 16 rows x 128 cols
//   (8 col-tiles). W^T staged bf16 in LDS [128][136] once/block; all 32
//   B-frags hoisted to VGPRs -> zero LDS traffic in the tile loop.
//   A-frags straight from global: A[m=lane&15][k=quad*8+j] = 16 B row chunk.
//   C/D: col=lane&15, row=quad*4+reg (HW-verified mapping).
//   SPLIT: z = z_hi + z_lo bf16 decomposition (fp32-accurate agg input).
//   MODE 0: y; 1: sigmoid(y); 2: layernorm(y)*gamma+beta (fp32 out).
// In-place safe: block reads only rows it owns, stores after its loads.
// ---------------------------------------------------------------------------
template <class HinT, class HoutT, int MODE, bool HAS_AGG, bool SPLIT>
__global__ __launch_bounds__(TPB) void mfma_gemm_kernel(
    const HinT* __restrict__ hin, const float* __restrict__ agg,
    const float* __restrict__ eps_ptr, int eps_idx,
    const float* __restrict__ W, const float* __restrict__ bias,
    const float* __restrict__ gamma, const float* __restrict__ beta,
    HoutT* __restrict__ out)
{
    __shared__ short sWt[128 * 136];   // bf16 W^T, padded row: 34.8 KB

    const int tid = threadIdx.x;
    // ---- stage W^T (fp32 -> bf16, transpose) ----
    #pragma unroll
    for (int it = 0; it < 8; ++it) {
        int idx = it * 256 + tid;
        int n = idx & 127, koct = idx >> 7;   // k octet
        float f[8];
        #pragma unroll
        for (int j = 0; j < 8; ++j) f[j] = W[(8 * koct + j) * 128 + n];
        uint4 u;
        u.x = pack2bf(f[0], f[1]); u.y = pack2bf(f[2], f[3]);
        u.z = pack2bf(f[4], f[5]); u.w = pack2bf(f[6], f[7]);
        *(uint4*)&sWt[n * 136 + 8 * koct] = u;
    }
    __syncthreads();

    const int lane = tid & 63, w = tid >> 6;
    const int m = lane & 15, quad = lane >> 4;

    // ---- hoist all B-fragments: bf[c*4+k0] = W^T[16c+m][32k0+8quad ..+7] ----
    short8 bf[32];
    #pragma unroll
    for (int c = 0; c < 8; ++c)
        #pragma unroll
        for (int k0 = 0; k0 < 4; ++k0)
            bf[c * 4 + k0] = *(const short8*)&sWt[(16 * c + m) * 136 + 32 * k0 + 8 * quad];

    const float scale = HAS_AGG ? (1.0f + eps_ptr[eps_idx]) : 1.0f;

    float bias_v[8];
    #pragma unroll
    for (int c = 0; c < 8; ++c) bias_v[c] = bias[16 * c + m];
    float g_v[8], bt_v[8];
    if (MODE == 2) {
        #pragma unroll
        for (int c = 0; c < 8; ++c) { g_v[c] = gamma[16 * c + m]; bt_v[c] = beta[16 * c + m]; }
    }

    for (int t = blockIdx.x; t < NTILES; t += gridDim.x) {
        const int arow = min(t * 64 + 16 * w + m, NNODES - 1);
        const size_t rbase = (size_t)arow * DIM;

        // ---- A-fragments (global), optional agg combine + hi/lo split ----
        short8 afh[4], afl[4];
        #pragma unroll
        for (int k0 = 0; k0 < 4; ++k0) {
            const int kb = 32 * k0 + 8 * quad;
            if (!HAS_AGG && sizeof(HinT) == 2) {
                afh[k0] = *(const short8*)((const bf16_t*)hin + rbase + kb);
            } else {
                float zf[8];
                if constexpr (sizeof(HinT) == 4) {
                    float4 h0 = *(const float4*)((const float*)hin + rbase + kb);
                    float4 h1 = *(const float4*)((const float*)hin + rbase + kb + 4);
                    zf[0] = h0.x; zf[1] = h0.y; zf[2] = h0.z; zf[3] = h0.w;
                    zf[4] = h1.x; zf[5] = h1.y; zf[6] = h1.z; zf[7] = h1.w;
                } else {
                    uint4 hu = *(const uint4*)((const bf16_t*)hin + rbase + kb);
                    zf[0] = bf_lo(hu.x); zf[1] = bf_hi(hu.x);
                    zf[2] = bf_lo(hu.y); zf[3] = bf_hi(hu.y);
                    zf[4] = bf_lo(hu.z); zf[5] = bf_hi(hu.z);
                    zf[6] = bf_lo(hu.w); zf[7] = bf_hi(hu.w);
                }
                if (HAS_AGG) {
                    float4 a0 = *(const float4*)(agg + rbase + kb);
                    float4 a1 = *(const float4*)(agg + rbase + kb + 4);
                    zf[0] = fmaf(scale, zf[0], a0.x); zf[1] = fmaf(scale, zf[1], a0.y);
                    zf[2] = fmaf(scale, zf[2], a0.z); zf[3] = fmaf(scale, zf[3], a0.w);
                    zf[4] = fmaf(scale, zf[4], a1.x); zf[5] = fmaf(scale, zf[5], a1.y);
                    zf[6] = fmaf(scale, zf[6], a1.z); zf[7] = fmaf(scale, zf[7], a1.w);
                }
                S8U hi;
                hi.us[0] = pack2bf(zf[0], zf[1]); hi.us[1] = pack2bf(zf[2], zf[3]);
                hi.us[2] = pack2bf(zf[4], zf[5]); hi.us[3] = pack2bf(zf[6], zf[7]);
                afh[k0] = hi.v;
                if (SPLIT) {
                    S8U lo;
                    float lw[8];
                    lw[0] = zf[0] - bf_lo(hi.us[0]); lw[1] = zf[1] - bf_hi(hi.us[0]);
                    lw[2] = zf[2] - bf_lo(hi.us[1]); lw[3] = zf[3] - bf_hi(hi.us[1]);
                    lw[4] = zf[4] - bf_lo(hi.us[2]); lw[5] = zf[5] - bf_hi(hi.us[2]);
                    lw[6] = zf[6] - bf_lo(hi.us[3]); lw[7] = zf[7] - bf_hi(hi.us[3]);
                    lo.us[0] = pack2bf(lw[0], lw[1]); lo.us[1] = pack2bf(lw[2], lw[3]);
                    lo.us[2] = pack2bf(lw[4], lw[5]); lo.us[3] = pack2bf(lw[6], lw[7]);
                    afl[k0] = lo.v;
                }
            }
        }

        // ---- MFMA ----
        f32x4 acc[8];
        #pragma unroll
        for (int c = 0; c < 8; ++c) acc[c] = (f32x4){0.f, 0.f, 0.f, 0.f};
        #pragma unroll
        for (int k0 = 0; k0 < 4; ++k0) {
            if (SPLIT) {
                #pragma unroll
                for (int c = 0; c < 8; ++c)
                    acc[c] = __builtin_amdgcn_mfma_f32_16x16x32_bf16(
                        afl[k0], bf[c * 4 + k0], acc[c], 0, 0, 0);
            }
            #pragma unroll
            for (int c = 0; c < 8; ++c)
                acc[c] = __builtin_amdgcn_mfma_f32_16x16x32_bf16(
                    afh[k0], bf[c * 4 + k0], acc[c], 0, 0, 0);
        }

        // ---- epilogue: row = t*64 + 16w + 4*quad + r, col = 16c + m ----
        const int row0 = t * 64 + 16 * w + 4 * quad;
        #pragma unroll
        for (int r = 0; r < 4; ++r) {
            const int grow = row0 + r;
            const bool ok = grow < NNODES;
            float y[8];
            #pragma unroll
            for (int c = 0; c < 8; ++c) y[c] = acc[c][r] + bias_v[c];
            if (MODE == 1) {
                #pragma unroll
                for (int c = 0; c < 8; ++c) y[c] = 1.0f / (1.0f + expf(-y[c]));
            } else if (MODE == 2) {
                float s1 = 0.f, s2 = 0.f;
                #pragma unroll
                for (int c = 0; c < 8; ++c) { s1 += y[c]; s2 = fmaf(y[c], y[c], s2); }
                #pragma unroll
                for (int d = 1; d < 16; d <<= 1) {   // reduce across 16-lane col group
                    s1 += __shfl_xor(s1, d);
                    s2 += __shfl_xor(s2, d);
                }
                float mean = s1 * (1.0f / DIM);
                float var  = s2 * (1.0f / DIM) - mean * mean;
                float rstd = rsqrtf(var + 1e-5f);
                #pragma unroll
                for (int c = 0; c < 8; ++c)
                    y[c] = fmaf((y[c] - mean) * rstd, g_v[c], bt_v[c]);
            }
            if (ok) {
                if constexpr (sizeof(HoutT) == 4) {
                    float* op = (float*)out + (size_t)grow * DIM + m;
                    #pragma unroll
                    for (int c = 0; c < 8; ++c) op[16 * c] = y[c];
                } else {
                    bf16_t* op = (bf16_t*)out + (size_t)grow * DIM + m;
                    #pragma unroll
                    for (int c = 0; c < 8; ++c) op[16 * c] = f2bf(y[c]);
                }
            }
        }
    }
}

// ---------------------------------------------------------------------------
// samples = mean + eps*std; eps = jax.random.normal(key(42)), partitionable
// threefry: block inputs (0, i), bits = out0 ^ out1, key (0,42).
// ---------------------------------------------------------------------------
__device__ __forceinline__ unsigned rotl32(unsigned x, int r) {
    return (x << r) | (x >> (32 - r));
}

__device__ __forceinline__ unsigned threefry_xor(unsigned c0, unsigned c1) {
    const unsigned k0 = 0u, k1 = 42u;
    const unsigned k2 = k0 ^ k1 ^ 0x1BD11BDAu;
    unsigned x0 = c0 + k0;
    unsigned x1 = c1 + k1;
#define TF_ROUND(R) { x0 += x1; x1 = rotl32(x1, R); x1 ^= x0; }
    TF_ROUND(13) TF_ROUND(15) TF_ROUND(26) TF_ROUND(6)
    x0 += k1; x1 += k2 + 1u;
    TF_ROUND(17) TF_ROUND(29) TF_ROUND(16) TF_ROUND(24)
    x0 += k2; x1 += k0 + 2u;
    TF_ROUND(13) TF_ROUND(15) TF_ROUND(26) TF_ROUND(6)
    x0 += k0; x1 += k1 + 3u;
    TF_ROUND(17) TF_ROUND(29) TF_ROUND(16) TF_ROUND(24)
    x0 += k1; x1 += k2 + 4u;
    TF_ROUND(13) TF_ROUND(15) TF_ROUND(26) TF_ROUND(6)
    x0 += k2; x1 += k0 + 5u;
#undef TF_ROUND
    return x0 ^ x1;
}

__device__ __forceinline__ float bits_to_normal(unsigned bits) {
    float f = __uint_as_float((bits >> 9) | 0x3F800000u) - 1.0f;
    const float lo = -0.99999994f;
    float u = __fadd_rn(__fmul_rn(f, 2.0f), lo);
    u = fmaxf(lo, u);
    float w = -log1pf(-(u * u));
    float p;
    if (w < 5.0f) {
        w -= 2.5f;
        p = 2.81022636e-08f;
        p = fmaf(p, w, 3.43273939e-07f);
        p = fmaf(p, w, -3.5233877e-06f);
        p = fmaf(p, w, -4.39150654e-06f);
        p = fmaf(p, w, 0.00021858087f);
        p = fmaf(p, w, -0.00125372503f);
        p = fmaf(p, w, -0.00417768164f);
        p = fmaf(p, w, 0.246640727f);
        p = fmaf(p, w, 1.50140941f);
    } else {
        w = sqrtf(w) - 3.0f;
        p = -0.000200214257f;
        p = fmaf(p, w, 0.000100950558f);
        p = fmaf(p, w, 0.00134934322f);
        p = fmaf(p, w, -0.00367342844f);
        p = fmaf(p, w, 0.00573950773f);
        p = fmaf(p, w, -0.0076224613f);
        p = fmaf(p, w, 0.00943887047f);
        p = fmaf(p, w, 1.00167406f);
        p = fmaf(p, w, 2.83297682f);
    }
    return 1.41421356f * (p * u);
}

__global__ __launch_bounds__(TPB) void samples_kernel(
    const float* __restrict__ mean_v, const float* __restrict__ std_v,
    float* __restrict__ samples)
{
    int t = blockIdx.x * TPB + threadIdx.x;
    if (t >= NHID / 4) return;
    float4 m = ((const float4*)mean_v)[t];
    float4 s = ((const float4*)std_v)[t];
    float e[4];
    #pragma unroll
    for (int q = 0; q < 4; q++) {
        unsigned i = 4u * (unsigned)t + (unsigned)q;
        e[q] = bits_to_normal(threefry_xor(0u, i));
    }
    float4 r;
    r.x = fmaf(e[0], s.x, m.x);
    r.y = fmaf(e[1], s.y, m.y);
    r.z = fmaf(e[2], s.z, m.z);
    r.w = fmaf(e[3], s.w, m.w);
    ((float4*)samples)[t] = r;
}

// ---------------------------------------------------------------------------
// Orchestration:
//   Dense-write CSR build (bin hist/scan/scatter + per-bin LDS counting
//   sort) -> per-node CSR; round-0 wave-per-node register gathers.
//   S region: bf16 h during GIN, fp32 samples at the end.
//   M: p0 aggs then mean_v.  V: shared l0 agg, p1 aggs, then std_v.
//   d_ws: gcnt[196] | start[197] | bcur[196] | off[50001] | bucket[NE].
// ---------------------------------------------------------------------------
extern "C" void kernel_launch(void* const* d_in, const int* in_sizes, int n_in,
                              void* d_out, int out_size, void* d_ws, size_t ws_size,
                              hipStream_t stream)
{
    const float* x     = (const float*)d_in[0];
    const int*   esrc  = (const int*)d_in[1];
    const int*   edst  = (const int*)d_in[2];
    const float* prm[2][7];
    for (int p = 0; p < 2; p++)
        for (int i = 0; i < 7; i++)
            prm[p][i] = (const float*)d_in[3 + p * 7 + i];
    const float* gamma = (const float*)d_in[17];
    const float* beta  = (const float*)d_in[18];

    float*  S  = (float*)d_out;
    bf16_t* Sb = (bf16_t*)d_out;
    float*  M  = S + NHID;
    float*  V  = M + NHID;

    int* gcnt  = (int*)d_ws;                       // NBINS
    int* start = gcnt + NBINS;                     // NBINS + 1
    int* bcur  = start + NBINS + 1;                // NBINS
    int* off   = bcur + NBINS;                     // NNODES + 1
    unsigned* bucket = (unsigned*)(off + NNODES + 1);  // NEDGES

    const dim3 gChunk(NCHUNKS);
    const dim3 gBin(NBINS);
    const dim3 gGather((NNODES + (TPB / 64) - 1) / (TPB / 64));
    const dim3 gGemm(512);
    const dim3 gSamp((NHID / 4 + TPB - 1) / TPB);

    hipMemsetAsync(gcnt, 0, NBINS * sizeof(int), stream);
    bin_hist_kernel<<<gChunk, TPB, 0, stream>>>(edst, gcnt);
    bin_scan_kernel<<<1, 64, 0, stream>>>(gcnt, start, bcur, off);
    bin_scatter_kernel<<<gChunk, TPB, 0, stream>>>(esrc, edst, bcur, bucket);
    build_csr_kernel<<<gBin, TPB, 0, stream>>>(start, bucket, off);

    // shared layer-0 aggregation (fp32 x)
    gather_agg_f32_kernel<<<gGather, TPB, 0, stream>>>(x, off, bucket, V);

    for (int p = 0; p < 2; p++) {
        const float* W1  = prm[p][0];
        const float* b1  = prm[p][1];
        const float* W2  = prm[p][2];
        const float* b2  = prm[p][3];
        const float* eps = prm[p][4];
        const float* Wo  = prm[p][5];
        const float* bo  = prm[p][6];
        float* AGG = (p == 0) ? M : V;
        float* OUT = (p == 0) ? M : V;

        // layer 0: fp32 x + shared agg (V), sigmoid, -> bf16 h
        mfma_gemm_kernel<float, bf16_t, 1, true, true><<<gGemm, TPB, 0, stream>>>(
            x, V, eps, 0, W1, b1, nullptr, nullptr, Sb);
        mfma_gemm_kernel<bf16_t, bf16_t, 0, false, false><<<gGemm, TPB, 0, stream>>>(
            Sb, nullptr, nullptr, 0, W2, b2, nullptr, nullptr, Sb);

        for (int l = 1; l < 3; l++) {
            gather_agg_bf16_kernel<<<gGather, TPB, 0, stream>>>(Sb, off, bucket, AGG);
            mfma_gemm_kernel<bf16_t, bf16_t, 1, true, true><<<gGemm, TPB, 0, stream>>>(
                Sb, AGG, eps, l, W1 + (size_t)l * DIM * DIM, b1 + l * DIM,
                nullptr, nullptr, Sb);
            mfma_gemm_kernel<bf16_t, bf16_t, 0, false, false><<<gGemm, TPB, 0, stream>>>(
                Sb, nullptr, nullptr, 0, W2 + (size_t)l * DIM * DIM, b2 + l * DIM,
                nullptr, nullptr, Sb);
        }

        mfma_gemm_kernel<bf16_t, float, 2, false, false><<<gGemm, TPB, 0, stream>>>(
            Sb, nullptr, nullptr, 0, Wo, bo, gamma, beta, OUT);
    }

    samples_kernel<<<gSamp, TPB, 0, stream>>>(M, V, S);
}

// Round 3
// 708.892 us; speedup vs baseline: 10.2021x; 1.1982x over previous
//
#include <hip/hip_runtime.h>
#include <math.h>

#define NNODES 50000
#define NEDGES 1600000
#define DIM    128
#define NHID   (NNODES * DIM)      // 6,400,000
#define TPB    256
#define NTILES ((NNODES + 63) / 64)   // 782, 64 rows per block-tile

// binned CSR build
#define NBINS  196                 // ceil(50000/256)
#define BINSZ  256                 // nodes per bin (dst>>8)
#define EPT    16                  // edges per thread in binning passes
#define CHUNK  (TPB * EPT)         // 4096 edges per block
#define NCHUNKS ((NEDGES + CHUNK - 1) / CHUNK)   // 391
#define BINCAP 10240               // staged edges per bin (mean 8192, sigma 90)

typedef unsigned short bf16_t;
typedef __attribute__((ext_vector_type(8))) short short8;   // 8 bf16, 4 VGPRs
typedef __attribute__((ext_vector_type(4))) float f32x4;    // MFMA acc

__device__ __forceinline__ float bf_lo(unsigned u) { return __uint_as_float(u << 16); }
__device__ __forceinline__ float bf_hi(unsigned u) { return __uint_as_float(u & 0xFFFF0000u); }
__device__ __forceinline__ bf16_t f2bf(float f) {   // RNE
    unsigned u = __float_as_uint(f);
    u += 0x7FFFu + ((u >> 16) & 1u);
    return (bf16_t)(u >> 16);
}
__device__ __forceinline__ unsigned pack2bf(float a, float b) {
    return (unsigned)f2bf(a) | ((unsigned)f2bf(b) << 16);
}

union S8U { short8 v; uint4 u4; unsigned us[4]; };

// ===========================================================================
// CSR build, dense-write pipeline:
//   bin_hist:    per-block LDS histogram of bin = dst>>8 -> 196 counters
//   bin_scan:    one wave scans 196 counts -> start[197], bcur; off[N]=NE
//   bin_scatter: per-block LDS-staged binning, one contiguous reservation
//                per bin per block -> dense packed writes (dl<<16 | src)
//   build_csr:   block per bin: stage edges in LDS, counting-sort by local
//                dst, emit per-node off[] and in-place sorted src bucket.
// All scattered 4B writes land in an L2-resident 32-40KB window => ~1x
// write amplification (vs 16x for the old per-node bucket_kernel).
// ===========================================================================
__global__ __launch_bounds__(TPB) void bin_hist_kernel(
    const int* __restrict__ dst, int* __restrict__ gcnt)
{
    __shared__ int lcnt[NBINS];
    const int tid = threadIdx.x;
    for (int i = tid; i < NBINS; i += TPB) lcnt[i] = 0;
    __syncthreads();
    const int base = blockIdx.x * CHUNK;
    #pragma unroll
    for (int k = 0; k < EPT; ++k) {
        int e = base + k * TPB + tid;
        if (e < NEDGES) atomicAdd(&lcnt[dst[e] >> 8], 1);
    }
    __syncthreads();
    for (int i = tid; i < NBINS; i += TPB) {
        int c = lcnt[i];
        if (c) atomicAdd(&gcnt[i], c);
    }
}

__global__ __launch_bounds__(64) void bin_scan_kernel(
    const int* __restrict__ gcnt, int* __restrict__ start, int* __restrict__ bcur,
    int* __restrict__ off)
{
    const int lane = threadIdx.x;   // 64 lanes, each owns 4 bins
    int c[4];
    int s = 0;
    #pragma unroll
    for (int k = 0; k < 4; ++k) {
        int b = 4 * lane + k;
        c[k] = (b < NBINS) ? gcnt[b] : 0;
        s += c[k];
    }
    int incl = s;
    #pragma unroll
    for (int d = 1; d < 64; d <<= 1) {
        int t = __shfl_up(incl, d);
        if (lane >= d) incl += t;
    }
    int excl = incl - s;
    #pragma unroll
    for (int k = 0; k < 4; ++k) {
        int b = 4 * lane + k;
        if (b < NBINS) { start[b] = excl; bcur[b] = excl; }
        excl += c[k];
    }
    if (lane == 63) { start[NBINS] = excl; off[NNODES] = excl; }   // == NEDGES
}

__global__ __launch_bounds__(TPB) void bin_scatter_kernel(
    const int* __restrict__ src, const int* __restrict__ dst,
    int* __restrict__ bcur, unsigned* __restrict__ bucket)
{
    __shared__ int lcnt[NBINS];    // phase A: counts
    __shared__ int lcur[NBINS];    // phase C: absolute cursors
    const int tid = threadIdx.x;
    for (int i = tid; i < NBINS; i += TPB) lcnt[i] = 0;
    __syncthreads();

    unsigned pk[EPT];
    int bn[EPT];
    const int base = blockIdx.x * CHUNK;
    #pragma unroll
    for (int k = 0; k < EPT; ++k) {
        int e = base + k * TPB + tid;
        int b = -1; unsigned p = 0;
        if (e < NEDGES) {
            int d = dst[e];
            int s = src[e];
            b = d >> 8;
            p = ((unsigned)(d & 255) << 16) | (unsigned)s;
            atomicAdd(&lcnt[b], 1);
        }
        pk[k] = p; bn[k] = b;
    }
    __syncthreads();
    for (int i = tid; i < NBINS; i += TPB) {
        int c = lcnt[i];
        lcur[i] = (c > 0) ? atomicAdd(&bcur[i], c) : 0;
    }
    __syncthreads();
    #pragma unroll
    for (int k = 0; k < EPT; ++k) {
        if (bn[k] >= 0) {
            int p = atomicAdd(&lcur[bn[k]], 1);
            bucket[p] = pk[k];
        }
    }
}

__global__ __launch_bounds__(TPB) void build_csr_kernel(
    const int* __restrict__ start, unsigned* __restrict__ bucket,
    int* __restrict__ off)
{
    __shared__ unsigned se[BINCAP];   // staged bin edges, 40 KB
    __shared__ int lcnt[BINSZ];
    __shared__ int lofs[BINSZ];
    __shared__ int wsum[4];
    const int tid = threadIdx.x;
    const int b = blockIdx.x;
    const int j0 = start[b], j1 = start[b + 1];
    const int n = j1 - j0;            // <= BINCAP by construction

    lcnt[tid] = 0;
    for (int i = tid; i < n; i += TPB) se[i] = bucket[j0 + i];
    __syncthreads();
    for (int i = tid; i < n; i += TPB) atomicAdd(&lcnt[se[i] >> 16], 1);
    __syncthreads();

    // exclusive scan of lcnt[256] across 4 waves
    const int lane = tid & 63, wid = tid >> 6;
    int v = lcnt[tid];
    int s = v;
    #pragma unroll
    for (int d = 1; d < 64; d <<= 1) {
        int t = __shfl_up(s, d);
        if (lane >= d) s += t;
    }
    if (lane == 63) wsum[wid] = s;
    __syncthreads();
    if (tid == 0) {
        int a = 0;
        #pragma unroll
        for (int k = 0; k < 4; ++k) { int t = wsum[k]; wsum[k] = a; a += t; }
    }
    __syncthreads();
    int excl = wsum[wid] + s - v;
    lofs[tid] = excl;
    int node = b * BINSZ + tid;
    if (node < NNODES) off[node] = j0 + excl;
    __syncthreads();

    // in-place counting-sort scatter (safe: all edges staged in LDS)
    for (int i = tid; i < n; i += TPB) {
        unsigned e = se[i];
        int pos = atomicAdd(&lofs[e >> 16], 1);
        bucket[j0 + pos] = e & 0xFFFFu;   // src node id
    }
}

// ---------------------------------------------------------------------------
// Gather aggregation, wave per node, 8-deep ILP: 8 independent row loads
// in flight per wave (latency was the round-2 bottleneck at 2-deep).
// ---------------------------------------------------------------------------
__global__ __launch_bounds__(TPB) void gather_agg_f32_kernel(
    const float* __restrict__ h, const int* __restrict__ off,
    const unsigned* __restrict__ bucket, float* __restrict__ agg)
{
    int node = blockIdx.x * (TPB / 64) + (threadIdx.x >> 6);
    int lane = threadIdx.x & 63;
    if (node >= NNODES) return;
    int j0 = off[node], j1 = off[node + 1];
    const float* base = h + 2 * lane;
    float ax = 0.0f, ay = 0.0f;
    int j = j0;
    for (; j + 8 <= j1; j += 8) {
        unsigned s[8];
        #pragma unroll
        for (int k = 0; k < 8; ++k) s[k] = bucket[j + k];
        float2 v[8];
        #pragma unroll
        for (int k = 0; k < 8; ++k) v[k] = *(const float2*)(base + (size_t)s[k] * DIM);
        #pragma unroll
        for (int k = 0; k < 8; ++k) { ax += v[k].x; ay += v[k].y; }
    }
    for (; j < j1; ++j) {
        float2 v0 = *(const float2*)(base + (size_t)bucket[j] * DIM);
        ax += v0.x; ay += v0.y;
    }
    *(float2*)(agg + (size_t)node * DIM + 2 * lane) = make_float2(ax, ay);
}

__global__ __launch_bounds__(TPB) void gather_agg_bf16_kernel(
    const bf16_t* __restrict__ hb, const int* __restrict__ off,
    const unsigned* __restrict__ bucket, float* __restrict__ agg)
{
    int node = blockIdx.x * (TPB / 64) + (threadIdx.x >> 6);
    int lane = threadIdx.x & 63;
    if (node >= NNODES) return;
    int j0 = off[node], j1 = off[node + 1];
    const unsigned* base = (const unsigned*)hb + lane;
    float ax = 0.0f, ay = 0.0f;
    int j = j0;
    for (; j + 8 <= j1; j += 8) {
        unsigned s[8];
        #pragma unroll
        for (int k = 0; k < 8; ++k) s[k] = bucket[j + k];
        unsigned u[8];
        #pragma unroll
        for (int k = 0; k < 8; ++k) u[k] = base[(size_t)s[k] * (DIM / 2)];
        #pragma unroll
        for (int k = 0; k < 8; ++k) { ax += bf_lo(u[k]); ay += bf_hi(u[k]); }
    }
    for (; j < j1; ++j) {
        unsigned u0 = base[(size_t)bucket[j] * (DIM / 2)];
        ax += bf_lo(u0); ay += bf_hi(u0);
    }
    *(float2*)(agg + (size_t)node * DIM + 2 * lane) = make_float2(ax, ay);
}

// ---------------------------------------------------------------------------
// MFMA GEMM: out[50000x128] = f( z @ W + bias ), z = scale*hin + agg (opt).
//   mfma_f32_16x16x32_bf16. Block = 4 waves; wave owns 16 rows x 128 cols
//   (8 col-tiles). W^T staged bf16 in LDS [128][136] once/block; all 32
//   B-frags hoisted to VGPRs -> zero LDS traffic in the tile loop.
//   A-frags straight from global: A[m=lane&15][k=quad*8+j] = 16 B row chunk.
//   C/D: col=lane&15, row=quad*4+reg (HW-verified mapping).
//   SPLIT: z = z_hi + z_lo bf16 decomposition (fp32-accurate agg input).
//   MODE 0: y; 1: sigmoid(y); 2: layernorm(y)*gamma+beta (fp32 out).
// In-place safe: block reads only rows it owns, stores after its loads.
// ---------------------------------------------------------------------------
template <class HinT, class HoutT, int MODE, bool HAS_AGG, bool SPLIT>
__global__ __launch_bounds__(TPB) void mfma_gemm_kernel(
    const HinT* __restrict__ hin, const float* __restrict__ agg,
    const float* __restrict__ eps_ptr, int eps_idx,
    const float* __restrict__ W, const float* __restrict__ bias,
    const float* __restrict__ gamma, const float* __restrict__ beta,
    HoutT* __restrict__ out)
{
    __shared__ short sWt[128 * 136];   // bf16 W^T, padded row: 34.8 KB

    const int tid = threadIdx.x;
    // ---- stage W^T (fp32 -> bf16, transpose) ----
    #pragma unroll
    for (int it = 0; it < 8; ++it) {
        int idx = it * 256 + tid;
        int n = idx & 127, koct = idx >> 7;   // k octet
        float f[8];
        #pragma unroll
        for (int j = 0; j < 8; ++j) f[j] = W[(8 * koct + j) * 128 + n];
        uint4 u;
        u.x = pack2bf(f[0], f[1]); u.y = pack2bf(f[2], f[3]);
        u.z = pack2bf(f[4], f[5]); u.w = pack2bf(f[6], f[7]);
        *(uint4*)&sWt[n * 136 + 8 * koct] = u;
    }
    __syncthreads();

    const int lane = tid & 63, w = tid >> 6;
    const int m = lane & 15, quad = lane >> 4;

    // ---- hoist all B-fragments: bf[c*4+k0] = W^T[16c+m][32k0+8quad ..+7] ----
    short8 bf[32];
    #pragma unroll
    for (int c = 0; c < 8; ++c)
        #pragma unroll
        for (int k0 = 0; k0 < 4; ++k0)
            bf[c * 4 + k0] = *(const short8*)&sWt[(16 * c + m) * 136 + 32 * k0 + 8 * quad];

    const float scale = HAS_AGG ? (1.0f + eps_ptr[eps_idx]) : 1.0f;

    float bias_v[8];
    #pragma unroll
    for (int c = 0; c < 8; ++c) bias_v[c] = bias[16 * c + m];
    float g_v[8], bt_v[8];
    if (MODE == 2) {
        #pragma unroll
        for (int c = 0; c < 8; ++c) { g_v[c] = gamma[16 * c + m]; bt_v[c] = beta[16 * c + m]; }
    }

    for (int t = blockIdx.x; t < NTILES; t += gridDim.x) {
        const int arow = min(t * 64 + 16 * w + m, NNODES - 1);
        const size_t rbase = (size_t)arow * DIM;

        // ---- A-fragments (global), optional agg combine + hi/lo split ----
        short8 afh[4], afl[4];
        #pragma unroll
        for (int k0 = 0; k0 < 4; ++k0) {
            const int kb = 32 * k0 + 8 * quad;
            if (!HAS_AGG && sizeof(HinT) == 2) {
                afh[k0] = *(const short8*)((const bf16_t*)hin + rbase + kb);
            } else {
                float zf[8];
                if constexpr (sizeof(HinT) == 4) {
                    float4 h0 = *(const float4*)((const float*)hin + rbase + kb);
                    float4 h1 = *(const float4*)((const float*)hin + rbase + kb + 4);
                    zf[0] = h0.x; zf[1] = h0.y; zf[2] = h0.z; zf[3] = h0.w;
                    zf[4] = h1.x; zf[5] = h1.y; zf[6] = h1.z; zf[7] = h1.w;
                } else {
                    uint4 hu = *(const uint4*)((const bf16_t*)hin + rbase + kb);
                    zf[0] = bf_lo(hu.x); zf[1] = bf_hi(hu.x);
                    zf[2] = bf_lo(hu.y); zf[3] = bf_hi(hu.y);
                    zf[4] = bf_lo(hu.z); zf[5] = bf_hi(hu.z);
                    zf[6] = bf_lo(hu.w); zf[7] = bf_hi(hu.w);
                }
                if (HAS_AGG) {
                    float4 a0 = *(const float4*)(agg + rbase + kb);
                    float4 a1 = *(const float4*)(agg + rbase + kb + 4);
                    zf[0] = fmaf(scale, zf[0], a0.x); zf[1] = fmaf(scale, zf[1], a0.y);
                    zf[2] = fmaf(scale, zf[2], a0.z); zf[3] = fmaf(scale, zf[3], a0.w);
                    zf[4] = fmaf(scale, zf[4], a1.x); zf[5] = fmaf(scale, zf[5], a1.y);
                    zf[6] = fmaf(scale, zf[6], a1.z); zf[7] = fmaf(scale, zf[7], a1.w);
                }
                S8U hi;
                hi.us[0] = pack2bf(zf[0], zf[1]); hi.us[1] = pack2bf(zf[2], zf[3]);
                hi.us[2] = pack2bf(zf[4], zf[5]); hi.us[3] = pack2bf(zf[6], zf[7]);
                afh[k0] = hi.v;
                if (SPLIT) {
                    S8U lo;
                    float lw[8];
                    lw[0] = zf[0] - bf_lo(hi.us[0]); lw[1] = zf[1] - bf_hi(hi.us[0]);
                    lw[2] = zf[2] - bf_lo(hi.us[1]); lw[3] = zf[3] - bf_hi(hi.us[1]);
                    lw[4] = zf[4] - bf_lo(hi.us[2]); lw[5] = zf[5] - bf_hi(hi.us[2]);
                    lw[6] = zf[6] - bf_lo(hi.us[3]); lw[7] = zf[7] - bf_hi(hi.us[3]);
                    lo.us[0] = pack2bf(lw[0], lw[1]); lo.us[1] = pack2bf(lw[2], lw[3]);
                    lo.us[2] = pack2bf(lw[4], lw[5]); lo.us[3] = pack2bf(lw[6], lw[7]);
                    afl[k0] = lo.v;
                }
            }
        }

        // ---- MFMA ----
        f32x4 acc[8];
        #pragma unroll
        for (int c = 0; c < 8; ++c) acc[c] = (f32x4){0.f, 0.f, 0.f, 0.f};
        #pragma unroll
        for (int k0 = 0; k0 < 4; ++k0) {
            if (SPLIT) {
                #pragma unroll
                for (int c = 0; c < 8; ++c)
                    acc[c] = __builtin_amdgcn_mfma_f32_16x16x32_bf16(
                        afl[k0], bf[c * 4 + k0], acc[c], 0, 0, 0);
            }
            #pragma unroll
            for (int c = 0; c < 8; ++c)
                acc[c] = __builtin_amdgcn_mfma_f32_16x16x32_bf16(
                    afh[k0], bf[c * 4 + k0], acc[c], 0, 0, 0);
        }

        // ---- epilogue: row = t*64 + 16w + 4*quad + r, col = 16c + m ----
        const int row0 = t * 64 + 16 * w + 4 * quad;
        #pragma unroll
        for (int r = 0; r < 4; ++r) {
            const int grow = row0 + r;
            const bool ok = grow < NNODES;
            float y[8];
            #pragma unroll
            for (int c = 0; c < 8; ++c) y[c] = acc[c][r] + bias_v[c];
            if (MODE == 1) {
                #pragma unroll
                for (int c = 0; c < 8; ++c) y[c] = 1.0f / (1.0f + expf(-y[c]));
            } else if (MODE == 2) {
                float s1 = 0.f, s2 = 0.f;
                #pragma unroll
                for (int c = 0; c < 8; ++c) { s1 += y[c]; s2 = fmaf(y[c], y[c], s2); }
                #pragma unroll
                for (int d = 1; d < 16; d <<= 1) {   // reduce across 16-lane col group
                    s1 += __shfl_xor(s1, d);
                    s2 += __shfl_xor(s2, d);
                }
                float mean = s1 * (1.0f / DIM);
                float var  = s2 * (1.0f / DIM) - mean * mean;
                float rstd = rsqrtf(var + 1e-5f);
                #pragma unroll
                for (int c = 0; c < 8; ++c)
                    y[c] = fmaf((y[c] - mean) * rstd, g_v[c], bt_v[c]);
            }
            if (ok) {
                if constexpr (sizeof(HoutT) == 4) {
                    float* op = (float*)out + (size_t)grow * DIM + m;
                    #pragma unroll
                    for (int c = 0; c < 8; ++c) op[16 * c] = y[c];
                } else {
                    bf16_t* op = (bf16_t*)out + (size_t)grow * DIM + m;
                    #pragma unroll
                    for (int c = 0; c < 8; ++c) op[16 * c] = f2bf(y[c]);
                }
            }
        }
    }
}

// ---------------------------------------------------------------------------
// samples = mean + eps*std; eps = jax.random.normal(key(42)), partitionable
// threefry: block inputs (0, i), bits = out0 ^ out1, key (0,42).
// ---------------------------------------------------------------------------
__device__ __forceinline__ unsigned rotl32(unsigned x, int r) {
    return (x << r) | (x >> (32 - r));
}

__device__ __forceinline__ unsigned threefry_xor(unsigned c0, unsigned c1) {
    const unsigned k0 = 0u, k1 = 42u;
    const unsigned k2 = k0 ^ k1 ^ 0x1BD11BDAu;
    unsigned x0 = c0 + k0;
    unsigned x1 = c1 + k1;
#define TF_ROUND(R) { x0 += x1; x1 = rotl32(x1, R); x1 ^= x0; }
    TF_ROUND(13) TF_ROUND(15) TF_ROUND(26) TF_ROUND(6)
    x0 += k1; x1 += k2 + 1u;
    TF_ROUND(17) TF_ROUND(29) TF_ROUND(16) TF_ROUND(24)
    x0 += k2; x1 += k0 + 2u;
    TF_ROUND(13) TF_ROUND(15) TF_ROUND(26) TF_ROUND(6)
    x0 += k0; x1 += k1 + 3u;
    TF_ROUND(17) TF_ROUND(29) TF_ROUND(16) TF_ROUND(24)
    x0 += k1; x1 += k2 + 4u;
    TF_ROUND(13) TF_ROUND(15) TF_ROUND(26) TF_ROUND(6)
    x0 += k2; x1 += k0 + 5u;
#undef TF_ROUND
    return x0 ^ x1;
}

__device__ __forceinline__ float bits_to_normal(unsigned bits) {
    float f = __uint_as_float((bits >> 9) | 0x3F800000u) - 1.0f;
    const float lo = -0.99999994f;
    float u = __fadd_rn(__fmul_rn(f, 2.0f), lo);
    u = fmaxf(lo, u);
    float w = -log1pf(-(u * u));
    float p;
    if (w < 5.0f) {
        w -= 2.5f;
        p = 2.81022636e-08f;
        p = fmaf(p, w, 3.43273939e-07f);
        p = fmaf(p, w, -3.5233877e-06f);
        p = fmaf(p, w, -4.39150654e-06f);
        p = fmaf(p, w, 0.00021858087f);
        p = fmaf(p, w, -0.00125372503f);
        p = fmaf(p, w, -0.00417768164f);
        p = fmaf(p, w, 0.246640727f);
        p = fmaf(p, w, 1.50140941f);
    } else {
        w = sqrtf(w) - 3.0f;
        p = -0.000200214257f;
        p = fmaf(p, w, 0.000100950558f);
        p = fmaf(p, w, 0.00134934322f);
        p = fmaf(p, w, -0.00367342844f);
        p = fmaf(p, w, 0.00573950773f);
        p = fmaf(p, w, -0.0076224613f);
        p = fmaf(p, w, 0.00943887047f);
        p = fmaf(p, w, 1.00167406f);
        p = fmaf(p, w, 2.83297682f);
    }
    return 1.41421356f * (p * u);
}

__global__ __launch_bounds__(TPB) void samples_kernel(
    const float* __restrict__ mean_v, const float* __restrict__ std_v,
    float* __restrict__ samples)
{
    int t = blockIdx.x * TPB + threadIdx.x;
    if (t >= NHID / 4) return;
    float4 m = ((const float4*)mean_v)[t];
    float4 s = ((const float4*)std_v)[t];
    float e[4];
    #pragma unroll
    for (int q = 0; q < 4; q++) {
        unsigned i = 4u * (unsigned)t + (unsigned)q;
        e[q] = bits_to_normal(threefry_xor(0u, i));
    }
    float4 r;
    r.x = fmaf(e[0], s.x, m.x);
    r.y = fmaf(e[1], s.y, m.y);
    r.z = fmaf(e[2], s.z, m.z);
    r.w = fmaf(e[3], s.w, m.w);
    ((float4*)samples)[t] = r;
}

// ---------------------------------------------------------------------------
// Orchestration:
//   Dense-write CSR build (bin hist/scan/scatter + per-bin LDS counting
//   sort) -> per-node CSR; wave-per-node 8-deep ILP gathers.
//   S region: bf16 h during GIN, fp32 samples at the end.
//   M: p0 aggs then mean_v.  V: shared l0 agg, p1 aggs, then std_v.
//   d_ws: gcnt[196] | start[197] | bcur[196] | off[50001] | bucket[NE].
// ---------------------------------------------------------------------------
extern "C" void kernel_launch(void* const* d_in, const int* in_sizes, int n_in,
                              void* d_out, int out_size, void* d_ws, size_t ws_size,
                              hipStream_t stream)
{
    const float* x     = (const float*)d_in[0];
    const int*   esrc  = (const int*)d_in[1];
    const int*   edst  = (const int*)d_in[2];
    const float* prm[2][7];
    for (int p = 0; p < 2; p++)
        for (int i = 0; i < 7; i++)
            prm[p][i] = (const float*)d_in[3 + p * 7 + i];
    const float* gamma = (const float*)d_in[17];
    const float* beta  = (const float*)d_in[18];

    float*  S  = (float*)d_out;
    bf16_t* Sb = (bf16_t*)d_out;
    float*  M  = S + NHID;
    float*  V  = M + NHID;

    int* gcnt  = (int*)d_ws;                       // NBINS
    int* start = gcnt + NBINS;                     // NBINS + 1
    int* bcur  = start + NBINS + 1;                // NBINS
    int* off   = bcur + NBINS;                     // NNODES + 1
    unsigned* bucket = (unsigned*)(off + NNODES + 1);  // NEDGES

    const dim3 gChunk(NCHUNKS);
    const dim3 gBin(NBINS);
    const dim3 gGather((NNODES + (TPB / 64) - 1) / (TPB / 64));
    const dim3 gGemm(512);
    const dim3 gSamp((NHID / 4 + TPB - 1) / TPB);

    hipMemsetAsync(gcnt, 0, NBINS * sizeof(int), stream);
    bin_hist_kernel<<<gChunk, TPB, 0, stream>>>(edst, gcnt);
    bin_scan_kernel<<<1, 64, 0, stream>>>(gcnt, start, bcur, off);
    bin_scatter_kernel<<<gChunk, TPB, 0, stream>>>(esrc, edst, bcur, bucket);
    build_csr_kernel<<<gBin, TPB, 0, stream>>>(start, bucket, off);

    // shared layer-0 aggregation (fp32 x)
    gather_agg_f32_kernel<<<gGather, TPB, 0, stream>>>(x, off, bucket, V);

    for (int p = 0; p < 2; p++) {
        const float* W1  = prm[p][0];
        const float* b1  = prm[p][1];
        const float* W2  = prm[p][2];
        const float* b2  = prm[p][3];
        const float* eps = prm[p][4];
        const float* Wo  = prm[p][5];
        const float* bo  = prm[p][6];
        float* AGG = (p == 0) ? M : V;
        float* OUT = (p == 0) ? M : V;

        // layer 0: fp32 x + shared agg (V), sigmoid, -> bf16 h
        mfma_gemm_kernel<float, bf16_t, 1, true, true><<<gGemm, TPB, 0, stream>>>(
            x, V, eps, 0, W1, b1, nullptr, nullptr, Sb);
        mfma_gemm_kernel<bf16_t, bf16_t, 0, false, false><<<gGemm, TPB, 0, stream>>>(
            Sb, nullptr, nullptr, 0, W2, b2, nullptr, nullptr, Sb);

        for (int l = 1; l < 3; l++) {
            gather_agg_bf16_kernel<<<gGather, TPB, 0, stream>>>(Sb, off, bucket, AGG);
            mfma_gemm_kernel<bf16_t, bf16_t, 1, true, true><<<gGemm, TPB, 0, stream>>>(
                Sb, AGG, eps, l, W1 + (size_t)l * DIM * DIM, b1 + l * DIM,
                nullptr, nullptr, Sb);
            mfma_gemm_kernel<bf16_t, bf16_t, 0, false, false><<<gGemm, TPB, 0, stream>>>(
                Sb, nullptr, nullptr, 0, W2 + (size_t)l * DIM * DIM, b2 + l * DIM,
                nullptr, nullptr, Sb);
        }

        mfma_gemm_kernel<bf16_t, float, 2, false, false><<<gGemm, TPB, 0, stream>>>(
            Sb, nullptr, nullptr, 0, Wo, bo, gamma, beta, OUT);
    }

    samples_kernel<<<gSamp, TPB, 0, stream>>>(M, V, S);
}